// Round 14
// baseline (278.162 us; speedup 1.0000x reference)
//
#include <hip/hip_runtime.h>
#include <math.h>

#define B_ 256
#define L_ 256
#define V_ 2048
#define DIN_ 128
#define H_ 256
#define NODES_ 511

typedef _Float16 half8 __attribute__((ext_vector_type(8)));
typedef float f32x4 __attribute__((ext_vector_type(4)));

__device__ __forceinline__ float sigm(float x) { return 1.f / (1.f + __expf(-x)); }
__device__ __forceinline__ float tanh_f(float x) {
    float xc = fminf(fmaxf(x, -15.f), 15.f);
    float e = __expf(2.f * xc);
    return (e - 1.f) / (e + 1.f);
}
__device__ __forceinline__ void gload16(const void* g, void* l) {
    __builtin_amdgcn_global_load_lds((const __attribute__((address_space(1))) unsigned int*)g,
                                     (__attribute__((address_space(3))) unsigned int*)l, 16, 0, 0);
}
template<int N> __device__ __forceinline__ void vwaitN() {
    asm volatile("s_waitcnt vmcnt(%0)" :: "i"(N) : "memory");
}

// WT[nn][k] fp16: FULL fused weights. nn = g*256+t (g:0=i,1=o,2=u,3=f0,4=f1),
// k: [0,128)=x, [128,384)=h1, [384,640)=h2
__global__ void build_WT(_Float16* __restrict__ WT,
    const float* __restrict__ Wioux, const float* __restrict__ Wfx,
    const float* __restrict__ Wiouh1, const float* __restrict__ Wfh11, const float* __restrict__ Wfh21,
    const float* __restrict__ Wiouh2, const float* __restrict__ Wfh12, const float* __restrict__ Wfh22)
{
    int e = blockIdx.x * 256 + threadIdx.x;   // < 1280*640
    int nn = e / 640, k = e - nn * 640;
    int g = nn >> 8, t = nn & 255;
    float v;
    if (k < 128) {
        v = (g < 3) ? Wioux[k * 768 + nn] : Wfx[k * 256 + t];
    } else if (k < 384) {
        int kp = k - 128;
        v = (g < 3) ? Wiouh1[kp * 768 + nn] : ((g == 3) ? Wfh11[kp * 256 + t] : Wfh21[kp * 256 + t]);
    } else {
        int kp = k - 384;
        v = (g < 3) ? Wiouh2[kp * 768 + nn] : ((g == 3) ? Wfh12[kp * 256 + t] : Wfh22[kp * 256 + t]);
    }
    WT[e] = (_Float16)v;
}

__global__ void build_bias(float* __restrict__ bias,
    const float* __restrict__ bioux, const float* __restrict__ biouh1, const float* __restrict__ biouh2,
    const float* __restrict__ bfx, const float* __restrict__ bfh11, const float* __restrict__ bfh12,
    const float* __restrict__ bfh21, const float* __restrict__ bfh22)
{
    int e = blockIdx.x * 256 + threadIdx.x;
    if (e >= 1280) return;
    int g = e >> 8, t = e & 255;
    float v;
    if (g < 3)       v = bioux[e] + biouh1[e] + biouh2[e];
    else if (g == 3) v = bfx[t] + bfh11[t] + bfh12[t];
    else             v = bfx[t] + bfh21[t] + bfh22[t];
    bias[e] = v;
}

// emb -> fp16, row 0 zeroed
__global__ void build_embh(_Float16* __restrict__ EH, const float* __restrict__ emb) {
    int e = blockIdx.x * 256 + threadIdx.x;   // < 2048*128
    EH[e] = (e < DIN_) ? (_Float16)0.f : (_Float16)emb[e];
}

// tab[id][col] f32 = emb(id,:) @ Wx_fused(:,col) + bias_total(col) — setup-only (feeds H0).
__global__ __launch_bounds__(256) void build_table(float* __restrict__ tab, const float* __restrict__ emb,
    const float* __restrict__ Wioux, const float* __restrict__ Wfx,
    const float* __restrict__ bioux, const float* __restrict__ biouh1, const float* __restrict__ biouh2,
    const float* __restrict__ bfx, const float* __restrict__ bfh11, const float* __restrict__ bfh12,
    const float* __restrict__ bfh21, const float* __restrict__ bfh22)
{
    __shared__ float As[64][33];
    __shared__ float Ws[32][65];
    const int tid = threadIdx.x, tx = tid & 15, ty = tid >> 4;
    const int i0 = blockIdx.x * 64, c0 = blockIdx.y * 64;
    const int g = c0 >> 8;
    float acc[4][4];
    #pragma unroll
    for (int i = 0; i < 4; ++i)
        #pragma unroll
        for (int j = 0; j < 4; ++j) acc[i][j] = 0.f;

    for (int k0 = 0; k0 < 128; k0 += 32) {
        #pragma unroll
        for (int it = 0; it < 2; ++it) {
            int f = tid + it * 256;
            int row = f >> 3, kk = (f & 7) * 4;
            int gr = i0 + row;
            float4 av = (gr == 0) ? make_float4(0.f, 0.f, 0.f, 0.f)
                                  : *(const float4*)(emb + (size_t)gr * 128 + k0 + kk);
            As[row][kk] = av.x; As[row][kk + 1] = av.y; As[row][kk + 2] = av.z; As[row][kk + 3] = av.w;
            int k = f >> 4, cc = (f & 15) * 4;
            int col = c0 + cc;
            float4 wv = (g < 3) ? *(const float4*)(Wioux + (size_t)(k0 + k) * 768 + col)
                                : *(const float4*)(Wfx + (size_t)(k0 + k) * 256 + (col & 255));
            Ws[k][cc] = wv.x; Ws[k][cc + 1] = wv.y; Ws[k][cc + 2] = wv.z; Ws[k][cc + 3] = wv.w;
        }
        __syncthreads();
        #pragma unroll 8
        for (int k = 0; k < 32; ++k) {
            float a[4], w[4];
            #pragma unroll
            for (int i = 0; i < 4; ++i) a[i] = As[ty * 4 + i][k];
            #pragma unroll
            for (int j = 0; j < 4; ++j) w[j] = Ws[k][tx * 4 + j];
            #pragma unroll
            for (int i = 0; i < 4; ++i)
                #pragma unroll
                for (int j = 0; j < 4; ++j) acc[i][j] = fmaf(a[i], w[j], acc[i][j]);
        }
        __syncthreads();
    }
    #pragma unroll
    for (int j = 0; j < 4; ++j) {
        int col = c0 + tx * 4 + j; int t = col & 255;
        float bs = (g < 3) ? (bioux[col] + biouh1[col] + biouh2[col])
                 : (g == 3) ? (bfx[t] + bfh11[t] + bfh12[t])
                            : (bfx[t] + bfh21[t] + bfh22[t]);
        #pragma unroll
        for (int i = 0; i < 4; ++i)
            tab[(size_t)(i0 + ty * 4 + i) * 1280 + col] = acc[i][j] + bs;
    }
}

// Level-0 result depends only on token id: H0h/H0c[id][t]
__global__ void build_h0c0(const float* __restrict__ tab, _Float16* __restrict__ H0h, float* __restrict__ H0c) {
    int id = blockIdx.x, t = threadIdx.x;
    const float* tp = tab + (size_t)id * 1280 + t;
    float vi = sigm(tp[0]), vo = sigm(tp[256]), vu = tanh_f(tp[512]);
    float c = vi * vu;
    H0h[id * 256 + t] = (_Float16)(vo * tanh_f(c));
    H0c[id * 256 + t] = c;
}

// Tree-level cell vJ: K=640 (x folded into GEMM; epilogue reads only the 5KB bias vec).
// m97-structure + counted-vmcnt 3-buffer pipeline (R12). BK=32, 20 K-steps.
// 0-conflict swizzle (R8-measured): slot j of row r holds k-seg j^((r>>1)&3).
// Steps: 0-3 x (embh gather), 4-11 h1, 12-19 h2.
template<bool LVL1, int RT>
__global__ __launch_bounds__(256, (RT >= 4 ? 2 : 4)) void cellJ(
    const _Float16* __restrict__ WT, const float* __restrict__ bias,
    const _Float16* __restrict__ embh, const int* __restrict__ ids,
    const _Float16* __restrict__ h_prev, const float* __restrict__ c_prev,
    _Float16* __restrict__ h_out, float* __restrict__ c_out,
    int n, int ln, int off, int nx)
{
    constexpr int BM = RT * 64;
    __shared__ __align__(16) char Asm[3][BM * 64];
    __shared__ __align__(16) char Bsm[3][5120];
    const int tid = threadIdx.x, lane = tid & 63, wid = tid >> 6;
    const int l15 = lane & 15, lg = lane >> 4;

    int bid = blockIdx.x, x, y;
    if ((nx & 7) == 0) { int xcd = bid & 7, rank = bid >> 3; x = xcd * (nx >> 3) + (rank >> 4); y = rank & 15; }
    else { x = bid >> 4; y = bid & 15; }
    const int rowB = x * BM;
    const int t0 = y * 16;

    // ---- A staging sources. Thread stages RT rows: rl=(wid*RT+i)*16+(lane>>2), slot lane&3.
    const unsigned segOff = (unsigned)((((lane & 3) ^ ((lane >> 3) & 3))) * 16);
    unsigned srcX[RT], srcA[RT], srcB1_[LVL1 ? RT : 1];
    #pragma unroll
    for (int i = 0; i < RT; ++i) {
        int rl = (wid * RT + i) * 16 + (lane >> 2);
        int r = rowB + rl;
        int b = r >> ln, j = r & (n - 1);
        srcX[i] = (unsigned)ids[b * NODES_ + off + j] * 256u + segOff;           // embh row=256B
        if constexpr (LVL1) {
            int bb = r >> 7, jj = r & 127;
            srcA[i]   = (unsigned)ids[bb * NODES_ + 2 * jj] * 512u + segOff;     // H0h row=512B
            srcB1_[i] = (unsigned)ids[bb * NODES_ + 2 * jj + 1] * 512u + segOff;
        } else {
            srcA[i] = (unsigned)r * 1024u + segOff;                               // [h1|h2]=1024B
        }
    }
    // ---- B staging sources (row stride 1280B)
    unsigned bsrc0, bsrc1 = 0;
    {
        int nr = tid >> 2, j = tid & 3;
        int ng = (nr >> 4) * 256 + t0 + (nr & 15);
        bsrc0 = (unsigned)((ng * 640 + ((j ^ ((nr >> 1) & 3)) * 8)) * 2);
        if (wid == 0) {
            int ng2 = 1024 + t0 + (tid >> 2);
            int seg2 = (tid & 3) ^ ((tid >> 3) & 3);
            bsrc1 = (unsigned)((ng2 * 640 + seg2 * 8) * 2);
        }
    }
    const char* hPB = (const char*)h_prev;
    const char* xPB = (const char*)embh;
    const char* wPB = (const char*)WT;

    f32x4 acc[RT][5];
    #pragma unroll
    for (int rt = 0; rt < RT; ++rt)
        #pragma unroll
        for (int g = 0; g < 5; ++g) acc[rt][g] = (f32x4)0.f;

    const int xw = (l15 >> 1) & 3;

    auto STAGE = [&](int st, int buf) {
        #pragma unroll
        for (int i = 0; i < RT; ++i) {
            const char* bp; unsigned sa;
            if (st < 4) { bp = xPB; sa = srcX[i] + (unsigned)st * 64u; }
            else if constexpr (LVL1) {
                bp = hPB;
                sa = (st < 12) ? (srcA[i] + (unsigned)(st - 4) * 64u)
                               : (srcB1_[i] + (unsigned)(st - 12) * 64u);
            } else { bp = hPB; sa = srcA[i] + (unsigned)(st - 4) * 64u; }
            gload16(bp + sa, &Asm[buf][(wid * RT + i) * 1024 + lane * 16]);
        }
        gload16(wPB + bsrc0 + (unsigned)st * 64u, &Bsm[buf][tid * 16]);
        if (wid == 0) gload16(wPB + bsrc1 + (unsigned)st * 64u, &Bsm[buf][4096 + tid * 16]);
    };
    auto COMPUTE = [&](int buf) {
        half8 aF[RT];
        #pragma unroll
        for (int rt = 0; rt < RT; ++rt)
            aF[rt] = *(const half8*)&Asm[buf][(wid * RT * 16 + rt * 16 + l15) * 64 + ((lg ^ xw) * 16)];
        #pragma unroll
        for (int g = 0; g < 5; ++g) {
            half8 bF = *(const half8*)&Bsm[buf][(g * 16 + l15) * 64 + ((lg ^ xw) * 16)];
            #pragma unroll
            for (int rt = 0; rt < RT; ++rt)
                acc[rt][g] = __builtin_amdgcn_mfma_f32_16x16x32_f16(aF[rt], bF, acc[rt][g], 0, 0, 0);
        }
    };
    auto WAITB = [&](bool counted) {
        if (counted) { if (wid == 0) vwaitN<RT + 2>(); else vwaitN<RT + 1>(); }
        else vwaitN<0>();
        __builtin_amdgcn_s_barrier();
        __builtin_amdgcn_sched_barrier(0);
    };

    STAGE(0, 0);
    STAGE(1, 1);
    WAITB(true);

    #pragma unroll
    for (int S = 0; S < 20; ++S) {
        if (S + 2 < 20) STAGE(S + 2, (S + 2) % 3);
        COMPUTE(S % 3);
        if (S < 19) WAITB(S + 2 < 20);
    }

    // ---- fused epilogue (bias-only; no tab). D: col = lane&15, row = (lane>>4)*4 + q
    const int tcol = t0 + l15;
    const float b0 = bias[tcol], b1 = bias[256 + tcol], b2 = bias[512 + tcol];
    const float b3 = bias[768 + tcol], b4 = bias[1024 + tcol];
    #pragma unroll
    for (int rt = 0; rt < RT; ++rt) {
        #pragma unroll
        for (int q = 0; q < 4; ++q) {
            int row = rowB + wid * (RT * 16) + rt * 16 + lg * 4 + q;
            float c1, c2;
            if constexpr (LVL1) {
                int bb = row >> 7, jj = row & 127;
                c1 = c_prev[(size_t)ids[bb * NODES_ + 2 * jj] * 256 + tcol];
                c2 = c_prev[(size_t)ids[bb * NODES_ + 2 * jj + 1] * 256 + tcol];
            } else {
                const float* cpp = c_prev + (size_t)row * 512 + tcol;
                c1 = cpp[0]; c2 = cpp[256];
            }
            float vi  = sigm(acc[rt][0][q] + b0);
            float vo  = sigm(acc[rt][1][q] + b1);
            float vu  = tanh_f(acc[rt][2][q] + b2);
            float vf0 = sigm(acc[rt][3][q] + b3);
            float vf1 = sigm(acc[rt][4][q] + b4);
            float c = vi * vu + vf0 * c1 + vf1 * c2;
            size_t ob = (size_t)row * 256 + tcol;
            h_out[ob] = (_Float16)(vo * tanh_f(c));
            c_out[ob] = c;
        }
    }
}

// pred[b] = relu(h_root[b] @ Wl1 + bl1) @ Wl2 + bl2
__global__ void head_kernel(const _Float16* __restrict__ hroot,
    const float* __restrict__ Wl1, const float* __restrict__ bl1,
    const float* __restrict__ Wl2, const float* __restrict__ bl2,
    float* __restrict__ out)
{
    __shared__ float hrow[H_];
    __shared__ float red[256];
    int b = blockIdx.x; int tid = threadIdx.x;
    hrow[tid] = (float)hroot[(size_t)b * H_ + tid];
    __syncthreads();
    float v = 0.f;
    if (tid < 100) {
        float s = bl1[tid];
        for (int k = 0; k < H_; ++k) s = fmaf(hrow[k], Wl1[k * 100 + tid], s);
        v = fmaxf(s, 0.f) * Wl2[tid];
    }
    red[tid] = v;
    __syncthreads();
    for (int s = 128; s > 0; s >>= 1) { if (tid < s) red[tid] += red[tid + s]; __syncthreads(); }
    if (tid == 0) out[b] = red[0] + bl2[0];
}

extern "C" void kernel_launch(void* const* d_in, const int* in_sizes, int n_in,
                              void* d_out, int out_size, void* d_ws, size_t ws_size,
                              hipStream_t stream) {
    const int*   ids    = (const int*)d_in[0];
    const float* emb    = (const float*)d_in[1];
    const float* Wioux  = (const float*)d_in[2];
    const float* bioux  = (const float*)d_in[3];
    const float* Wiouh1 = (const float*)d_in[4];
    const float* biouh1 = (const float*)d_in[5];
    const float* Wiouh2 = (const float*)d_in[6];
    const float* biouh2 = (const float*)d_in[7];
    const float* Wfx    = (const float*)d_in[8];
    const float* bfx    = (const float*)d_in[9];
    const float* Wfh11  = (const float*)d_in[10];
    const float* bfh11  = (const float*)d_in[11];
    const float* Wfh12  = (const float*)d_in[12];
    const float* bfh12  = (const float*)d_in[13];
    const float* Wfh21  = (const float*)d_in[14];
    const float* bfh21  = (const float*)d_in[15];
    const float* Wfh22  = (const float*)d_in[16];
    const float* bfh22  = (const float*)d_in[17];
    const float* Wl1    = (const float*)d_in[18];
    const float* bl1    = (const float*)d_in[19];
    const float* Wl2    = (const float*)d_in[20];
    const float* bl2    = (const float*)d_in[21];
    float* out = (float*)d_out;

    // ws layout (bytes)
    char* wsb = (char*)d_ws;
    _Float16* WT   = (_Float16*)(wsb);                   //  1,638,400
    _Float16* embh = (_Float16*)(wsb + 1638400);         //    524,288
    float*    bias = (float*)(wsb + 2162688);            //      5,120
    float*    tab  = (float*)(wsb + 2167808);            // 10,485,760 (setup only)
    _Float16* H0h  = (_Float16*)(wsb + 12653568);        //  1,048,576
    float*    H0c  = (float*)(wsb + 13702144);           //  2,097,152
    _Float16* hA   = (_Float16*)(wsb + 15799296);        //  8,388,608
    _Float16* hB   = (_Float16*)(wsb + 24187904);        // 16,777,216
    float*    cA   = (float*)(wsb + 40965120);           // 16,777,216
    float*    cB   = (float*)(wsb + 57742336);           // 33,554,432 -> ends 91,296,768

    build_WT<<<dim3(3200), 256, 0, stream>>>(WT, Wioux, Wfx, Wiouh1, Wfh11, Wfh21, Wiouh2, Wfh12, Wfh22);
    build_bias<<<dim3(5), 256, 0, stream>>>(bias, bioux, biouh1, biouh2, bfx, bfh11, bfh12, bfh21, bfh22);
    build_embh<<<dim3(1024), 256, 0, stream>>>(embh, emb);
    build_table<<<dim3(32, 20), 256, 0, stream>>>(tab, emb, Wioux, Wfx,
        bioux, biouh1, biouh2, bfx, bfh11, bfh12, bfh21, bfh22);
    build_h0c0<<<dim3(2048), 256, 0, stream>>>(tab, H0h, H0c);

    // level 1: M=32768 rows, nx=128
    cellJ<true, 4><<<dim3(2048), 256, 0, stream>>>(WT, bias, embh, ids, H0h, H0c, hB, cB, 128, 7, 256, 128);

    _Float16 *hp = hB, *hn = hA;
    float    *cp = cB, *cn = cA;
    int off = 384, n = 64, ln = 6;
    for (int lvl = 2; lvl <= 8; ++lvl) {
        int M = B_ * n;
        if (M >= 2048) {                 // lvl 2-5: RT=4, BM=256
            int nx = M / 256;
            cellJ<false, 4><<<dim3(nx * 16), 256, 0, stream>>>(WT, bias, embh, ids, hp, cp, hn, cn, n, ln, off, nx);
        } else if (M >= 1024) {          // lvl 6: RT=2, BM=128
            int nx = M / 128;
            cellJ<false, 2><<<dim3(nx * 16), 256, 0, stream>>>(WT, bias, embh, ids, hp, cp, hn, cn, n, ln, off, nx);
        } else {                         // lvl 7-8: RT=1, BM=64
            int nx = M / 64;
            cellJ<false, 1><<<dim3(nx * 16), 256, 0, stream>>>(WT, bias, embh, ids, hp, cp, hn, cn, n, ln, off, nx);
        }
        off += n; n >>= 1; --ln;
        _Float16* t1 = hp; hp = hn; hn = t1;
        float*    t2 = cp; cp = cn; cn = t2;
    }

    head_kernel<<<dim3(256), 256, 0, stream>>>(hp, Wl1, bl1, Wl2, bl2, out);
}